// Round 20
// baseline (38.676 us; speedup 1.0000x reference)
//
#include <hip/hip_runtime.h>
#include <math.h>

#define NCH 256        // simplex chunks (grid_ect = 2*NCH = 512, 2/CU)
#define RSL 8          // reduction slices
#define FPS 32768.0f   // fixed-point scale 2^15 for transition sums

typedef int iv4 __attribute__((ext_vector_type(4)));

// K1: lane-per-simplex saturation-split ECT.
// r16-r19 diagnosis: cold-replay ect (27us vs 8.8us hot) is L2-miss/L3-hit
// LATENCY with tiny per-instruction MLP (old layout: 16 theta-lanes
// broadcast one simplex -> 4 line-requests per load instruction).
// New layout: thread = one simplex for all 16 thetas of its half ->
// every gather instruction issues 64 independent line requests (16x MLP),
// and the idx->x dependent chain is paid once per simplex, amortized over
// 16 thetas of register compute. batch gathers eliminated: batch is sorted,
// so g = 7 compares vs graph boundaries (binary-searched once per block).
// Hist relayout [arr][t16][g][bin] (theta uniform per deposit step); bin
// XOR-swizzled with (g&3)<<3 to spread Gaussian-clustered bins across
// banks. LDS int atomics only -> deterministic. Flush = nontemporal int4.
__global__ __launch_bounds__(1024) void ect_kernel(const float* __restrict__ x,
    const float* __restrict__ v, const int* __restrict__ ei,
    const int* __restrict__ face, const int* __restrict__ batch,
    const float* __restrict__ lin, const int* __restrict__ scale_p,
    int* __restrict__ partial, int N, int E, int F, int M, int csz) {
  __shared__ alignas(16) int hist[8192];  // arr*4096 + t16*256 + g*32 + binsw
  __shared__ int bnds[8];
  int tid = threadIdx.x, bid = blockIdx.x;
  int c = bid >> 1, hf = bid & 1;
#pragma unroll
  for (int i = 0; i < 2; ++i)
    ((int4*)hist)[tid + 1024 * i] = int4{0, 0, 0, 0};
  if (tid < 8) {  // bnds[k] = first node index of graph k (batch sorted)
    int lo = 0, hi = N;
    while (lo < hi) {
      int mid = (lo + hi) >> 1;
      if (batch[mid] < tid) lo = mid + 1; else hi = mid;
    }
    bnds[tid] = lo;
  }
  __syncthreads();

  int start = c * csz;
  int nrem = min(csz, M - start);
  bool active = tid < nrem;

  // load this lane's simplex vertices (per-lane scattered -> 64-wide MLP)
  float ax = 0, ay = 0, az = 0, bx = 0, by = 0, bz = 0, cx = 0, cy = 0, cz = 0;
  int nv = 0, g = 0, isn = 0;
  if (active) {
    int m = start + tid;
    int n0;
    if (m < N) {
      n0 = m; nv = 1; isn = 1;
    } else if (m < N + E) {
      int e = m - N;
      n0 = ei[e];
      int n1 = ei[E + e];
      bx = x[3 * n1]; by = x[3 * n1 + 1]; bz = x[3 * n1 + 2];
      nv = 2; isn = -1;
    } else {
      int f = m - N - E;
      n0 = face[f];
      int n1 = face[F + f], n2 = face[2 * F + f];
      bx = x[3 * n1]; by = x[3 * n1 + 1]; bz = x[3 * n1 + 2];
      cx = x[3 * n2]; cy = x[3 * n2 + 1]; cz = x[3 * n2 + 2];
      nv = 3; isn = 1;
    }
    ax = x[3 * n0]; ay = x[3 * n0 + 1]; az = x[3 * n0 + 2];
#pragma unroll
    for (int k = 1; k < 8; ++k) g += (n0 >= bnds[k]);
  }
  float fsn = (float)isn;

  float scale = (float)scale_p[0];
  float lin0 = lin[0];
  float step = (lin[31] - lin0) * (1.f / 31.f);
  float istep = 1.f / step;
  float Cl = scale * step * 1.44269504088896f;  // log2-slope per bin
  float w = 13.f / (scale * step);              // transition half-width (bins)
  int gsw = (g & 3) << 3;                       // bank-spread swizzle
  int gb = g << 5;

#pragma unroll
  for (int ch = 0; ch < 2; ++ch) {
    float vx[8], vy[8], vz[8];  // uniform -> scalar regs
#pragma unroll
    for (int k = 0; k < 8; ++k) {
      int tg = (hf << 4) + (ch << 3) + k;
      vx[k] = v[tg]; vy[k] = v[32 + tg]; vz[k] = v[64 + tg];
    }
    if (active) {
#pragma unroll
      for (int k = 0; k < 8; ++k) {
        float h = fmaf(ax, vx[k], fmaf(ay, vy[k], az * vz[k]));
        if (nv > 1) h = fmaxf(h, fmaf(bx, vx[k], fmaf(by, vy[k], bz * vz[k])));
        if (nv > 2) h = fmaxf(h, fmaf(cx, vx[k], fmaf(cy, vy[k], cz * vz[k])));
        int base = (((ch << 3) + k) << 8) + gb;
        float kf = (h - lin0) * istep;
        int fs = max((int)floorf(kf + w) + 1, 0);
        if (fs <= 31) atomicAdd(&hist[base + (fs ^ gsw)], isn);
        float bf = rintf(kf);
        float d = kf - bf;
        if (fabsf(d) <= w) {
          int b = (int)bf;
          if ((unsigned)b <= 31u) {
            float e2 = __builtin_amdgcn_exp2f(Cl * d);
            float val = fsn * __builtin_amdgcn_rcpf(1.f + e2);
            atomicAdd(&hist[4096 + base + (b ^ gsw)], (int)rintf(val * FPS));
          }
        }
      }
    }
  }
  __syncthreads();
  // flush: nontemporal int4 — keep the 16.8MB partial stream out of L2
  iv4* dst = (iv4*)(partial + (size_t)bid * 8192);
  const iv4* src = (const iv4*)hist;
#pragma unroll
  for (int i = 0; i < 2; ++i)
    __builtin_nontemporal_store(src[tid + 1024 * i], &dst[tid + 1024 * i]);
}

// K2: tree reduce over chunks (layout-agnostic elementwise sum).
// 512 blocks: s = bid>>6, cg = bid&63; cid = cg*256+tid.
__global__ __launch_bounds__(256) void reduce_kernel(const int* __restrict__ partial,
    int* __restrict__ part2) {
  int tid = threadIdx.x, bid = blockIdx.x;
  int s = bid >> 6, cg = bid & 63;
  int cid = cg * 256 + tid;
  int hf = cid >> 13, j = cid & 8191;
  int sum = 0;
  for (int cc = s; cc < NCH; cc += RSL)
    sum += partial[(size_t)(cc * 2 + hf) * 8192 + j];
  part2[s * 16384 + cid] = sum;
}

// K3: per-graph block (8 x 1024). Cell layout now
// hf*8192 + arr*4096 + t16*256 + g*32 + (b ^ ((g&3)<<3)).
// Sum RSL slices, Hillis-Steele prefix of markers over logical bins, add
// fractional transitions, per-graph max, normalize, write out.
__global__ __launch_bounds__(1024) void fin_kernel(const int* __restrict__ part2,
    float* __restrict__ out) {
  __shared__ float sP[32][33];
  __shared__ float wmax[16];
  int g = blockIdx.x, tid = threadIdx.x;
  int b = tid >> 5, t = tid & 31;
  int hf = t >> 4, t16 = t & 15;
  int bp = b ^ ((g & 3) << 3);                       // unswizzle
  int jc = (hf << 13) + (t16 << 8) + (g << 5) + bp;  // marker cell
  int ja = jc + 4096;                                // transition cell
  int sc = 0, sa = 0;
#pragma unroll
  for (int s = 0; s < RSL; ++s) {
    sc += part2[s * 16384 + jc];
    sa += part2[s * 16384 + ja];
  }
  sP[b][t] = (float)sc;
  __syncthreads();
#pragma unroll
  for (int st = 1; st < 32; st <<= 1) {
    float add = (b >= st) ? sP[b - st][t] : 0.f;
    __syncthreads();
    sP[b][t] += add;
    __syncthreads();
  }
  float r = sP[b][t] + (float)sa * (1.f / FPS);
  float m = r;
#pragma unroll
  for (int off = 32; off > 0; off >>= 1) m = fmaxf(m, __shfl_down(m, off));
  if ((tid & 63) == 0) wmax[tid >> 6] = m;
  __syncthreads();
  if (tid == 0) {
    float mm = wmax[0];
#pragma unroll
    for (int ww = 1; ww < 16; ++ww) mm = fmaxf(mm, wmax[ww]);
    wmax[0] = mm;
  }
  __syncthreads();
  out[(size_t)g * 1024 + tid] = r / wmax[0];
}

extern "C" void kernel_launch(void* const* d_in, const int* in_sizes, int n_in,
                              void* d_out, int out_size, void* d_ws, size_t ws_size,
                              hipStream_t stream) {
  const float* x     = (const float*)d_in[0];
  const float* v     = (const float*)d_in[1];
  const float* lin   = (const float*)d_in[2];
  const int*   ei    = (const int*)d_in[3];
  const int*   face  = (const int*)d_in[4];
  const int*   batch = (const int*)d_in[5];
  const int*   scale = (const int*)d_in[6];
  const int N = in_sizes[5];
  const int E = in_sizes[3] / 2;
  const int F = in_sizes[4] / 3;
  const int M = N + E + F;
  const int csz = (M + NCH - 1) / NCH;   // simplices per chunk (~704, <=1024)

  int* partial = (int*)d_ws;                          // 2*NCH*8192 ints
  int* part2   = partial + (size_t)2 * NCH * 8192;    // RSL*16384 ints

  ect_kernel<<<2 * NCH, 1024, 0, stream>>>(x, v, ei, face, batch, lin, scale,
                                           partial, N, E, F, M, csz);
  reduce_kernel<<<64 * RSL, 256, 0, stream>>>(partial, part2);
  fin_kernel<<<8, 1024, 0, stream>>>(part2, (float*)d_out);
}

// Round 21
// 32.828 us; speedup vs baseline: 1.1781x; 1.1781x over previous
//
#include <hip/hip_runtime.h>
#include <math.h>

#define NCH 256        // number of simplex chunks (grid_ect = 2*NCH = 512)
#define RSL 8          // reduction slices
#define FPS 32768.0f   // fixed-point scale 2^15 for transition sums

typedef int iv4 __attribute__((ext_vector_type(4)));

// FINAL (r19 = banked best, 32.65us). Structure: ect -> reduce -> fin.
// ect: raw-order saturation-split ECT. Block = (chunk c, theta-half hf);
// 1024 threads = (srow 0..63, t16 0..15); 2 blocks/CU = 8 waves/SIMD (HW
// max). Per (simplex,theta): sigmoid only in the <=2 transition bins
// (2^15 fixed point) + one saturated-region marker; prefix-sum in fin
// reconstructs the full [32][32] grid. LDS hist [arr][g][bin][t16] = 32KB,
// LDS int atomics only (order-independent -> deterministic; 16 t16-lanes
// of each quarter-wave hit distinct addresses). Flush = nontemporal int4
// stores (keeps the 16.8MB partial stream out of L2; inputs stay resident).
// Floor ledger (r10-r20): occupancy maxed, ILP-2 null, line-count null,
// warm-sweep negative, sequential-records negative (first-touch cost
// conserved), lane-per-simplex negative (same-address LDS atomics).
// 32.65us = 8.8 hot-VALU + ~17 first-touch L2-miss latency + ~7 reduce/
// fin/launch-gaps.
__global__ __launch_bounds__(1024) void ect_kernel(const float* __restrict__ x,
    const float* __restrict__ v, const int* __restrict__ ei,
    const int* __restrict__ face, const int* __restrict__ batch,
    const float* __restrict__ lin, const int* __restrict__ scale_p,
    int* __restrict__ partial, int N, int E, int F, int M, int csz) {
  __shared__ alignas(16) int hist[8192];  // arr*4096 + g*512 + bin*16 + t16
  int tid = threadIdx.x, bid = blockIdx.x;
  int c = bid >> 1, hf = bid & 1;
#pragma unroll
  for (int i = 0; i < 2; ++i)
    ((int4*)hist)[tid + 1024 * i] = int4{0, 0, 0, 0};
  __syncthreads();

  int t16 = tid & 15, srow = tid >> 4;    // srow 0..63
  int tt = (hf << 4) + t16;               // global theta
  float v0 = v[tt], v1 = v[32 + tt], v2 = v[64 + tt];
  int start = c * csz;
  int end = min(start + csz, M);

  float scale = (float)scale_p[0];
  float lin0 = lin[0];
  float step = (lin[31] - lin0) * (1.f / 31.f);
  float istep = 1.f / step;
  float Cl = scale * step * 1.44269504088896f;  // log2-slope per bin
  float w = 13.f / (scale * step);              // transition half-width (bins)

  auto dot3 = [&](int n) {
    return fmaf(x[3 * n], v0, fmaf(x[3 * n + 1], v1, x[3 * n + 2] * v2));
  };
  auto deposit = [&](float h, int g, int isn) {
    float kf = (h - lin0) * istep;
    int b0 = (int)ceilf(kf - w);
    int b1 = (int)floorf(kf + w);
    int fs = max(b1 + 1, 0);
    int gb = g << 9;
    if (fs <= 31) atomicAdd(&hist[gb + (fs << 4) + t16], isn);
    float q = Cl * kf;
    float fsn = (float)isn;
    int blo = max(b0, 0), bhi = min(b1, 31);
    for (int b = blo; b <= bhi; ++b) {
      float e2 = __builtin_amdgcn_exp2f(fmaf(-Cl, (float)b, q));
      float val = fsn * __builtin_amdgcn_rcpf(1.f + e2);
      atomicAdd(&hist[4096 + gb + (b << 4) + t16], (int)rintf(val * FPS));
    }
  };

  // nodes
  int e0 = min(end, N);
  for (int m = start + srow; m < e0; m += 64)
    deposit(dot3(m), batch[m], 1);
  // edges (max over 2 endpoints, sign -1)
  int s1 = max(start, N), e1 = min(end, N + E);
  for (int m = s1 + srow; m < e1; m += 64) {
    int e = m - N;
    int n0 = ei[e], n1 = ei[E + e];
    deposit(fmaxf(dot3(n0), dot3(n1)), batch[n0], -1);
  }
  // faces (max over 3 vertices, sign +1)
  int s2 = max(start, N + E);
  for (int m = s2 + srow; m < end; m += 64) {
    int f = m - N - E;
    int n0 = face[f], n1 = face[F + f], n2 = face[2 * F + f];
    deposit(fmaxf(fmaxf(dot3(n0), dot3(n1)), dot3(n2)), batch[n0], 1);
  }
  __syncthreads();
  // flush: NONTEMPORAL int4 stores — keep partial out of L2
  iv4* dst = (iv4*)(partial + (size_t)bid * 8192);
  const iv4* src = (const iv4*)hist;
#pragma unroll
  for (int i = 0; i < 2; ++i)
    __builtin_nontemporal_store(src[tid + 1024 * i], &dst[tid + 1024 * i]);
}

// K2: tree reduce over chunks. 512 blocks: s = bid>>6 (0..7), cg = bid&63;
// cell cid = cg*256+tid; cid = hf*8192 + (arr*4096 + g*512 + bin*16 + t16).
// Plain coalesced loads/stores, no atomics.
__global__ __launch_bounds__(256) void reduce_kernel(const int* __restrict__ partial,
    int* __restrict__ part2) {
  int tid = threadIdx.x, bid = blockIdx.x;
  int s = bid >> 6, cg = bid & 63;
  int cid = cg * 256 + tid;
  int hf = cid >> 13, j = cid & 8191;
  int sum = 0;
  for (int cc = s; cc < NCH; cc += RSL)
    sum += partial[(size_t)(cc * 2 + hf) * 8192 + j];
  part2[s * 16384 + cid] = sum;
}

// K3: per-graph block (8 x 1024): sum RSL slices, Hillis-Steele prefix of
// markers over bins, add fractional transitions, per-graph max, normalize.
__global__ __launch_bounds__(1024) void fin_kernel(const int* __restrict__ part2,
    float* __restrict__ out) {
  __shared__ float sP[32][33];
  __shared__ float wmax[16];
  int g = blockIdx.x, tid = threadIdx.x;
  int b = tid >> 5, t = tid & 31;
  int hf = t >> 4, t16 = t & 15;
  int jc = (hf << 13) + (g << 9) + (b << 4) + t16;  // marker cell
  int ja = jc + 4096;                               // transition cell
  int sc = 0, sa = 0;
#pragma unroll
  for (int s = 0; s < RSL; ++s) {
    sc += part2[s * 16384 + jc];
    sa += part2[s * 16384 + ja];
  }
  sP[b][t] = (float)sc;
  __syncthreads();
#pragma unroll
  for (int st = 1; st < 32; st <<= 1) {
    float add = (b >= st) ? sP[b - st][t] : 0.f;
    __syncthreads();
    sP[b][t] += add;
    __syncthreads();
  }
  float r = sP[b][t] + (float)sa * (1.f / FPS);
  float m = r;
#pragma unroll
  for (int off = 32; off > 0; off >>= 1) m = fmaxf(m, __shfl_down(m, off));
  if ((tid & 63) == 0) wmax[tid >> 6] = m;
  __syncthreads();
  if (tid == 0) {
    float mm = wmax[0];
#pragma unroll
    for (int ww = 1; ww < 16; ++ww) mm = fmaxf(mm, wmax[ww]);
    wmax[0] = mm;
  }
  __syncthreads();
  out[(size_t)g * 1024 + tid] = r / wmax[0];
}

extern "C" void kernel_launch(void* const* d_in, const int* in_sizes, int n_in,
                              void* d_out, int out_size, void* d_ws, size_t ws_size,
                              hipStream_t stream) {
  const float* x     = (const float*)d_in[0];
  const float* v     = (const float*)d_in[1];
  const float* lin   = (const float*)d_in[2];
  const int*   ei    = (const int*)d_in[3];
  const int*   face  = (const int*)d_in[4];
  const int*   batch = (const int*)d_in[5];
  const int*   scale = (const int*)d_in[6];
  const int N = in_sizes[5];
  const int E = in_sizes[3] / 2;
  const int F = in_sizes[4] / 3;
  const int M = N + E + F;
  const int csz = (M + NCH - 1) / NCH;   // simplices per chunk (~704)

  int* partial = (int*)d_ws;                          // 2*NCH*8192 ints
  int* part2   = partial + (size_t)2 * NCH * 8192;    // RSL*16384 ints

  ect_kernel<<<2 * NCH, 1024, 0, stream>>>(x, v, ei, face, batch, lin, scale,
                                           partial, N, E, F, M, csz);
  reduce_kernel<<<64 * RSL, 256, 0, stream>>>(partial, part2);
  fin_kernel<<<8, 1024, 0, stream>>>(part2, (float*)d_out);
}